// Round 11
// baseline (223.725 us; speedup 1.0000x reference)
//
#include <hip/hip_runtime.h>
#include <math.h>

#define TT 512
#define BB 64
#define II 256
#define HH 512
#define BH (BB*HH)           // 32768
#define TBH ((size_t)TT*BH)  // 16777216
#define MM (TT*BB)           // 32768

typedef float f32x4 __attribute__((ext_vector_type(4)));
typedef float f32x2 __attribute__((ext_vector_type(2)));
typedef _Float16 f16x8 __attribute__((ext_vector_type(8)));
typedef _Float16 f16x2 __attribute__((ext_vector_type(2)));
typedef unsigned short u16;

template<typename T> struct V2;
template<> struct V2<float>    { typedef f32x2 type; };
template<> struct V2<_Float16> { typedef f16x2 type; };

// ---------------------------------------------------------------------------
// Pack W0,W1 [N][K] f32 -> fragment-major f16 (8 f16 = 16 B per fragment)
// ---------------------------------------------------------------------------
__global__ __launch_bounds__(256)
void pack_w2(const float* __restrict__ W0, const float* __restrict__ W1,
             _Float16* __restrict__ P0, _Float16* __restrict__ P1,
             int nf0, int nf1)
{
    const int i = blockIdx.x * 256 + threadIdx.x;
    const float* src; _Float16* dst;
    if (i < nf0) { src = W0 + (size_t)i * 8;  dst = P0 + (size_t)i * 8; }
    else         { const int j = i - nf0; if (j >= nf1) return;
                   src = W1 + (size_t)j * 8;  dst = P1 + (size_t)j * 8; }
    f16x8 h8;
#pragma unroll
    for (int j = 0; j < 8; ++j) h8[j] = (_Float16)src[j];
    *(f16x8*)dst = h8;
}

// ---------------------------------------------------------------------------
// GEMM, A = f32 (reg-staged, cvt f16 during LDS stage; round-7 proven).
// ---------------------------------------------------------------------------
template<typename OutT>
__global__ __launch_bounds__(256, 4)
void gemm_f32a(const float* __restrict__ A, const _Float16* __restrict__ Bp,
               const float* __restrict__ bias, OutT* __restrict__ C,
               int M, int N, int K)
{
    const int K8 = K >> 3;
    __shared__ _Float16 As[128][40];   // padded: row stride 80 B

    const int tid  = threadIdx.x;
    const int lane = tid & 63;
    const int wid  = tid >> 6;
    const int wr   = wid >> 1, wc = wid & 1;

    const int nbn = N >> 7;
    const int nt  = (M >> 7) * nbn;
    const int per = nt >> 3;
    const int logical = (blockIdx.x & 7) * per + (blockIdx.x >> 3);
    const int bm = logical / nbn;
    const int bn = logical % nbn;
    const int row0 = bm * 128;
    const int col0 = bn * 128;

    const int s_row = tid >> 1;
    const int s_kh  = (tid & 1) * 16;
    const float* Ap = A + (size_t)(row0 + s_row) * K + s_kh;

    const int fr  = lane & 15;
    const int q   = lane >> 4;
    const int ko8 = q * 8;

    f32x4 acc[4][4];
#pragma unroll
    for (int m = 0; m < 4; ++m)
#pragma unroll
        for (int n = 0; n < 4; ++n)
#pragma unroll
            for (int r = 0; r < 4; ++r) acc[m][n][r] = 0.f;

    const _Float16* bbase[4];
#pragma unroll
    for (int n = 0; n < 4; ++n) {
        const int col = col0 + wc * 64 + n * 16 + fr;
        bbase[n] = Bp + ((size_t)col * K8 + q) * 8;
    }

    f32x4 a_ld[4];
#pragma unroll
    for (int qq = 0; qq < 4; ++qq) a_ld[qq] = *(const f32x4*)(Ap + qq * 4);

    const int nkt = K >> 5;
    for (int kt = 0; kt < nkt; ++kt) {
        __syncthreads();
#pragma unroll
        for (int half = 0; half < 2; ++half) {
            f16x8 h8;
#pragma unroll
            for (int j = 0; j < 8; ++j)
                h8[j] = (_Float16)a_ld[half * 2 + (j >> 2)][j & 3];
            *(f16x8*)&As[s_row][s_kh + half * 8] = h8;
        }
        __syncthreads();

        f16x8 bfr[4];
#pragma unroll
        for (int n = 0; n < 4; ++n)
            bfr[n] = *(const f16x8*)(bbase[n] + (size_t)kt * 32);

        if (kt + 1 < nkt) {
            const float* apn = Ap + (size_t)(kt + 1) * 32;
#pragma unroll
            for (int qq = 0; qq < 4; ++qq) a_ld[qq] = *(const f32x4*)(apn + qq * 4);
        }

#pragma unroll
        for (int m = 0; m < 4; ++m) {
            const int row = wr * 64 + m * 16 + fr;
            f16x8 af = *(const f16x8*)&As[row][ko8];
#pragma unroll
            for (int n = 0; n < 4; ++n)
                acc[m][n] = __builtin_amdgcn_mfma_f32_16x16x32_f16(af, bfr[n], acc[m][n], 0, 0, 0);
        }
    }

#pragma unroll
    for (int n = 0; n < 4; ++n) {
        const int gc = col0 + wc * 64 + n * 16 + fr;
        const float bj = bias[gc];
#pragma unroll
        for (int m = 0; m < 4; ++m) {
            const int gr0 = row0 + wr * 64 + m * 16 + q * 4;
#pragma unroll
            for (int r = 0; r < 4; ++r)
                C[(size_t)(gr0 + r) * N + gc] = (OutT)(acc[m][n][r] + bj);
        }
    }
}

// ---------------------------------------------------------------------------
// GEMM, A = f16 (reg-staged: 2x16B loads/thread/K-step, no cvt).
// ---------------------------------------------------------------------------
template<typename OutT>
__global__ __launch_bounds__(256, 4)
void gemm_f16a_reg(const _Float16* __restrict__ A, const _Float16* __restrict__ Bp,
                   const float* __restrict__ bias, OutT* __restrict__ C,
                   int M, int N, int K)
{
    const int K8 = K >> 3;
    __shared__ _Float16 As[128][40];

    const int tid  = threadIdx.x;
    const int lane = tid & 63;
    const int wid  = tid >> 6;
    const int wr   = wid >> 1, wc = wid & 1;

    const int nbn = N >> 7;
    const int nt  = (M >> 7) * nbn;
    const int per = nt >> 3;
    const int logical = (blockIdx.x & 7) * per + (blockIdx.x >> 3);
    const int bm = logical / nbn;
    const int bn = logical % nbn;
    const int row0 = bm * 128;
    const int col0 = bn * 128;

    const int s_row = tid >> 1;
    const int s_kh  = (tid & 1) * 16;
    const _Float16* Ap = A + (size_t)(row0 + s_row) * K + s_kh;

    const int fr  = lane & 15;
    const int q   = lane >> 4;
    const int ko8 = q * 8;

    f32x4 acc[4][4];
#pragma unroll
    for (int m = 0; m < 4; ++m)
#pragma unroll
        for (int n = 0; n < 4; ++n)
#pragma unroll
            for (int r = 0; r < 4; ++r) acc[m][n][r] = 0.f;

    const _Float16* bbase[4];
#pragma unroll
    for (int n = 0; n < 4; ++n) {
        const int col = col0 + wc * 64 + n * 16 + fr;
        bbase[n] = Bp + ((size_t)col * K8 + q) * 8;
    }

    f16x8 a_ld[2];
#pragma unroll
    for (int hh = 0; hh < 2; ++hh) a_ld[hh] = *(const f16x8*)(Ap + hh * 8);

    const int nkt = K >> 5;
    for (int kt = 0; kt < nkt; ++kt) {
        __syncthreads();
#pragma unroll
        for (int hh = 0; hh < 2; ++hh)
            *(f16x8*)&As[s_row][s_kh + hh * 8] = a_ld[hh];
        __syncthreads();

        f16x8 bfr[4];
#pragma unroll
        for (int n = 0; n < 4; ++n)
            bfr[n] = *(const f16x8*)(bbase[n] + (size_t)kt * 32);

        if (kt + 1 < nkt) {
            const _Float16* apn = Ap + (size_t)(kt + 1) * 32;
#pragma unroll
            for (int hh = 0; hh < 2; ++hh) a_ld[hh] = *(const f16x8*)(apn + hh * 8);
        }

#pragma unroll
        for (int m = 0; m < 4; ++m) {
            const int row = wr * 64 + m * 16 + fr;
            f16x8 af = *(const f16x8*)&As[row][ko8];
#pragma unroll
            for (int n = 0; n < 4; ++n)
                acc[m][n] = __builtin_amdgcn_mfma_f32_16x16x32_f16(af, bfr[n], acc[m][n], 0, 0, 0);
        }
    }

#pragma unroll
    for (int n = 0; n < 4; ++n) {
        const int gc = col0 + wc * 64 + n * 16 + fr;
        const float bj = bias[gc];
#pragma unroll
        for (int m = 0; m < 4; ++m) {
            const int gr0 = row0 + wr * 64 + m * 16 + q * 4;
#pragma unroll
            for (int r = 0; r < 4; ++r)
                C[(size_t)(gr0 + r) * N + gc] = (OutT)(acc[m][n][r] + bj);
        }
    }
}

// ---------------------------------------------------------------------------
// Recurrence, 2 h-adjacent chains per thread (vectorized VMEM: dword loads
// of f16 pairs, dwordx2 f32 stores, dword f16 stores -> half the VMEM instrs
// and vmcnt pressure of the scalar version). 16-step blocks, 4-deep named-
// buffer pipeline (loads issue >=3 blocks before use; no rotation moves;
// storage-type buffers, cvt at use). Per-chain arithmetic identical to the
// scalar version. Fallback (PreT=f32): pre aliases go; reads of block tb
// happen >=3 blocks before writes to tb (same thread, program order).
// ---------------------------------------------------------------------------
template<typename PreT, bool EMITF16, bool NTX, bool NTG>
__global__ __launch_bounds__(64)
void skip_indrnn_rec2(const PreT* __restrict__ pre, const float* __restrict__ h0,
                      const float* __restrict__ w_hh, const float* __restrict__ w_uh,
                      const float* __restrict__ b_uh, int layer,
                      float* __restrict__ xo, float* __restrict__ go,
                      _Float16* __restrict__ xo16)
{
    typedef typename V2<PreT>::type Pre2;

    const int p    = blockIdx.x * 64 + threadIdx.x;   // [0, BH/2)
    const int base = p * 2;                            // two flat (b,h) slots
    const int hh0  = base & (HH - 1);                  // even h; hh0+1 same b

    float whh0 = fminf(fmaxf(w_hh[layer * HH + hh0],     -1000.f), 1000.f);
    float whh1 = fminf(fmaxf(w_hh[layer * HH + hh0 + 1], -1000.f), 1000.f);
    const float wuh0 = w_uh[layer * HH + hh0];
    const float wuh1 = w_uh[layer * HH + hh0 + 1];
    const float buh  = b_uh[layer];

    float hx0 = h0[layer * HH + hh0];
    float hx1 = h0[layer * HH + hh0 + 1];
    float up0 = 1.f, up1 = 1.f;
    float cum0 = 0.f, cum1 = 0.f;

    const int SB = 16;
    const int NB = TT / SB;              // 32 blocks, stepped 4 at a time

    Pre2 b0[SB], b1[SB], b2[SB], b3[SB];

#define LOADB(buf, blk)                                                    \
    {   const int _b = (blk);                                              \
        _Pragma("unroll")                                                  \
        for (int j = 0; j < SB; ++j)                                       \
            buf[j] = *(const Pre2*)&pre[(size_t)(_b * SB + j) * BH + base];\
    }

#define COMPUTEB(buf, blk)                                                 \
    {   const int _t0 = (blk) * SB;                                        \
        _Pragma("unroll")                                                  \
        for (int j = 0; j < SB; ++j) {                                     \
            const int t = _t0 + j;                                         \
            const float pv0 = (float)buf[j][0];                            \
            const float pv1 = (float)buf[j][1];                            \
            const float nhx0 = fmaxf(fmaf(whh0, hx0, pv0), 0.f);           \
            const float nhx1 = fmaxf(fmaf(whh1, hx1, pv1), 0.f);           \
            const float z0 = fmaf(nhx0, wuh0, buh);                        \
            const float z1 = fmaf(nhx1, wuh1, buh);                        \
            const float ti0 = 1.f / (1.f + __expf(-z0));                   \
            const float ti1 = 1.f / (1.f + __expf(-z1));                   \
            const float c0 = cum0 + fminf(up0, 1.f - cum0);                \
            const float c1 = cum1 + fminf(up1, 1.f - cum1);                \
            const float g0v = rintf(c0);                                   \
            const float g1v = rintf(c1);                                   \
            const float nh0 = (g0v > 0.5f) ? nhx0 : hx0;                   \
            const float nh1 = (g1v > 0.5f) ? nhx1 : hx1;                   \
            const float nu0 = (g0v > 0.5f) ? ti0 : up0;                    \
            const float nu1 = (g1v > 0.5f) ? ti1 : up1;                    \
            const float nc0 = (g0v > 0.5f) ? 0.f : c0;                     \
            const float nc1 = (g1v > 0.5f) ? 0.f : c1;                     \
            f32x2 xv; xv[0] = nh0; xv[1] = nh1;                            \
            f32x2 gv; gv[0] = g0v; gv[1] = g1v;                            \
            if (NTX) __builtin_nontemporal_store(xv, (f32x2*)&xo[(size_t)t * BH + base]); \
            else     *(f32x2*)&xo[(size_t)t * BH + base] = xv;             \
            if (NTG) __builtin_nontemporal_store(gv, (f32x2*)&go[(size_t)t * BH + base]); \
            else     *(f32x2*)&go[(size_t)t * BH + base] = gv;             \
            if (EMITF16) {                                                 \
                f16x2 hv; hv[0] = (_Float16)nh0; hv[1] = (_Float16)nh1;    \
                *(f16x2*)&xo16[(size_t)t * BH + base] = hv;                \
            }                                                              \
            hx0 = nh0; up0 = nu0; cum0 = nc0;                              \
            hx1 = nh1; up1 = nu1; cum1 = nc1;                              \
        }                                                                  \
    }

    LOADB(b0, 0);
    LOADB(b1, 1);
    LOADB(b2, 2);

    for (int tb = 0; tb < NB; tb += 4) {
        if (tb + 3 < NB) LOADB(b3, tb + 3);
        COMPUTEB(b0, tb);
        if (tb + 4 < NB) LOADB(b0, tb + 4);
        COMPUTEB(b1, tb + 1);
        if (tb + 5 < NB) LOADB(b1, tb + 5);
        COMPUTEB(b2, tb + 2);
        if (tb + 6 < NB) LOADB(b2, tb + 6);
        COMPUTEB(b3, tb + 3);
    }
#undef LOADB
#undef COMPUTEB
}

// ---------------------------------------------------------------------------
// d_ws plan (ws = 1 GiB per observed fills; need ~97 MiB):
//   P0 @0, P1 @256 KB, pre0 f16 @1 MiB, pre1 f16 @33 MiB, xo0h f16 @65 MiB.
// d_out = pure outputs. Fallback (small ws) = in-d_out plan, all f32.
// ---------------------------------------------------------------------------
extern "C" void kernel_launch(void* const* d_in, const int* in_sizes, int n_in,
                              void* d_out, int out_size, void* d_ws, size_t ws_size,
                              hipStream_t stream) {
    const float* x    = (const float*)d_in[0];
    const float* h0   = (const float*)d_in[1];
    const float* W0   = (const float*)d_in[2];
    const float* W1   = (const float*)d_in[3];
    const float* b_ih = (const float*)d_in[4];
    const float* w_hh = (const float*)d_in[5];
    const float* w_uh = (const float*)d_in[6];
    const float* b_uh = (const float*)d_in[7];

    float* out = (float*)d_out;
    float* X0 = out;
    float* X1 = out + TBH;
    float* G0 = out + 2 * TBH;
    float* G1 = out + 3 * TBH;

    const int nf0 = HH * II / 8;          // 16384
    const int nf1 = HH * HH / 8;          // 32768
    const int recgrid = (BH / 2) / 64;    // 256 blocks

    if (ws_size >= (size_t)100 * 1024 * 1024) {
        char* ws = (char*)d_ws;
        _Float16* P0   = (_Float16*)ws;
        _Float16* P1   = (_Float16*)(ws + (size_t)256 * 1024);
        _Float16* pre0 = (_Float16*)(ws + (size_t)1  * 1024 * 1024);
        _Float16* pre1 = (_Float16*)(ws + (size_t)33 * 1024 * 1024);
        _Float16* xo0h = (_Float16*)(ws + (size_t)65 * 1024 * 1024);

        pack_w2<<<(nf0 + nf1 + 255) / 256, 256, 0, stream>>>(W0, W1, P0, P1, nf0, nf1);

        gemm_f32a<_Float16><<<1024, 256, 0, stream>>>(x, P0, b_ih, pre0, MM, HH, II);
        skip_indrnn_rec2<_Float16, true, true, true><<<recgrid, 64, 0, stream>>>(
            pre0, h0, w_hh, w_uh, b_uh, 0, X0, G0, xo0h);
        gemm_f16a_reg<_Float16><<<1024, 256, 0, stream>>>(xo0h, P1, b_ih + HH, pre1, MM, HH, HH);
        skip_indrnn_rec2<_Float16, false, true, true><<<recgrid, 64, 0, stream>>>(
            pre1, h0, w_hh, w_uh, b_uh, 1, X1, G1, nullptr);
    } else {
        _Float16* P0 = (_Float16*)X1;
        _Float16* P1 = P0 + (size_t)nf0 * 8;
        float* pre = G1;

        pack_w2<<<(nf0 + nf1 + 255) / 256, 256, 0, stream>>>(W0, W1, P0, P1, nf0, nf1);

        gemm_f32a<float><<<1024, 256, 0, stream>>>(x, P0, b_ih, pre, MM, HH, II);
        skip_indrnn_rec2<float, false, false, true><<<recgrid, 64, 0, stream>>>(
            pre, h0, w_hh, w_uh, b_uh, 0, X0, G0, nullptr);
        gemm_f32a<float><<<1024, 256, 0, stream>>>(X0, P1, b_ih + HH, pre, MM, HH, HH);
        skip_indrnn_rec2<float, false, true, true><<<recgrid, 64, 0, stream>>>(
            pre, h0, w_hh, w_uh, b_uh, 1, X1, G1, nullptr);
    }
}

// Round 12
// 207.462 us; speedup vs baseline: 1.0784x; 1.0784x over previous
//
#include <hip/hip_runtime.h>
#include <math.h>

#define TT 512
#define BB 64
#define II 256
#define HH 512
#define BH (BB*HH)           // 32768
#define TBH ((size_t)TT*BH)  // 16777216
#define MM (TT*BB)           // 32768

typedef float f32x4 __attribute__((ext_vector_type(4)));
typedef _Float16 f16x8 __attribute__((ext_vector_type(8)));
typedef unsigned short u16;

// ---------------------------------------------------------------------------
// Pack W0,W1 [N][K] f32 -> fragment-major f16 (8 f16 = 16 B per fragment)
// ---------------------------------------------------------------------------
__global__ __launch_bounds__(256)
void pack_w2(const float* __restrict__ W0, const float* __restrict__ W1,
             _Float16* __restrict__ P0, _Float16* __restrict__ P1,
             int nf0, int nf1)
{
    const int i = blockIdx.x * 256 + threadIdx.x;
    const float* src; _Float16* dst;
    if (i < nf0) { src = W0 + (size_t)i * 8;  dst = P0 + (size_t)i * 8; }
    else         { const int j = i - nf0; if (j >= nf1) return;
                   src = W1 + (size_t)j * 8;  dst = P1 + (size_t)j * 8; }
    f16x8 h8;
#pragma unroll
    for (int j = 0; j < 8; ++j) h8[j] = (_Float16)src[j];
    *(f16x8*)dst = h8;
}

// ---------------------------------------------------------------------------
// GEMM, A = f32 (reg-staged, cvt f16 during LDS stage; round-7 proven).
//   C[M][N] = A[M][K] * W_f16[N][K]^T + bias ; OutT = f16 (pre) or f32
// 128x128 tile, BK=32, 4 waves (2x2), 4x4 16x16x32 f16 frags.
// A-prefetch for kt+1 issued before the MFMA block (latency overlapped).
// Tile order: bn-major + XCD-clustered.
// ---------------------------------------------------------------------------
template<typename OutT>
__global__ __launch_bounds__(256, 4)
void gemm_f32a(const float* __restrict__ A, const _Float16* __restrict__ Bp,
               const float* __restrict__ bias, OutT* __restrict__ C,
               int M, int N, int K)
{
    const int K8 = K >> 3;
    __shared__ _Float16 As[128][40];   // padded: row stride 80 B

    const int tid  = threadIdx.x;
    const int lane = tid & 63;
    const int wid  = tid >> 6;
    const int wr   = wid >> 1, wc = wid & 1;

    const int nbn = N >> 7;
    const int nt  = (M >> 7) * nbn;
    const int per = nt >> 3;
    const int logical = (blockIdx.x & 7) * per + (blockIdx.x >> 3);
    const int bm = logical / nbn;
    const int bn = logical % nbn;
    const int row0 = bm * 128;
    const int col0 = bn * 128;

    const int s_row = tid >> 1;
    const int s_kh  = (tid & 1) * 16;
    const float* Ap = A + (size_t)(row0 + s_row) * K + s_kh;

    const int fr  = lane & 15;
    const int q   = lane >> 4;
    const int ko8 = q * 8;

    f32x4 acc[4][4];
#pragma unroll
    for (int m = 0; m < 4; ++m)
#pragma unroll
        for (int n = 0; n < 4; ++n)
#pragma unroll
            for (int r = 0; r < 4; ++r) acc[m][n][r] = 0.f;

    const _Float16* bbase[4];
#pragma unroll
    for (int n = 0; n < 4; ++n) {
        const int col = col0 + wc * 64 + n * 16 + fr;
        bbase[n] = Bp + ((size_t)col * K8 + q) * 8;
    }

    f32x4 a_ld[4];
#pragma unroll
    for (int qq = 0; qq < 4; ++qq) a_ld[qq] = *(const f32x4*)(Ap + qq * 4);

    const int nkt = K >> 5;
    for (int kt = 0; kt < nkt; ++kt) {
        __syncthreads();
#pragma unroll
        for (int half = 0; half < 2; ++half) {
            f16x8 h8;
#pragma unroll
            for (int j = 0; j < 8; ++j)
                h8[j] = (_Float16)a_ld[half * 2 + (j >> 2)][j & 3];
            *(f16x8*)&As[s_row][s_kh + half * 8] = h8;
        }
        __syncthreads();

        f16x8 bfr[4];
#pragma unroll
        for (int n = 0; n < 4; ++n)
            bfr[n] = *(const f16x8*)(bbase[n] + (size_t)kt * 32);

        if (kt + 1 < nkt) {
            const float* apn = Ap + (size_t)(kt + 1) * 32;
#pragma unroll
            for (int qq = 0; qq < 4; ++qq) a_ld[qq] = *(const f32x4*)(apn + qq * 4);
        }

#pragma unroll
        for (int m = 0; m < 4; ++m) {
            const int row = wr * 64 + m * 16 + fr;
            f16x8 af = *(const f16x8*)&As[row][ko8];
#pragma unroll
            for (int n = 0; n < 4; ++n)
                acc[m][n] = __builtin_amdgcn_mfma_f32_16x16x32_f16(af, bfr[n], acc[m][n], 0, 0, 0);
        }
    }

#pragma unroll
    for (int n = 0; n < 4; ++n) {
        const int gc = col0 + wc * 64 + n * 16 + fr;
        const float bj = bias[gc];
#pragma unroll
        for (int m = 0; m < 4; ++m) {
            const int gr0 = row0 + wr * 64 + m * 16 + q * 4;
#pragma unroll
            for (int r = 0; r < 4; ++r)
                C[(size_t)(gr0 + r) * N + gc] = (OutT)(acc[m][n][r] + bj);
        }
    }
}

// ---------------------------------------------------------------------------
// Recurrence: one thread per (b,h) [512 waves = max TLP — round-11 lesson:
// do NOT widen per-thread at the cost of wave count]. 16-step blocks,
// 4-deep MANUAL pipeline with named buffers (no rotation moves; buffers in
// storage type, cvt at use; loads issue >=3 blocks (~1500 cy) before use).
// Fallback (PreT=f32): pre aliases go; reads of block tb happen >=3 blocks
// before writes to tb (same thread, program order).
// ---------------------------------------------------------------------------
template<typename PreT, bool NTX, bool NTG>
__global__ __launch_bounds__(64)
void skip_indrnn_rec(const PreT* __restrict__ pre, const float* __restrict__ h0,
                     const float* __restrict__ w_hh, const float* __restrict__ w_uh,
                     const float* __restrict__ b_uh, int layer,
                     float* __restrict__ xo, float* __restrict__ go)
{
    const int idx = blockIdx.x * 64 + threadIdx.x;
    const int h = idx & (HH - 1);

    float whh = w_hh[layer * HH + h];
    whh = fminf(fmaxf(whh, -1000.f), 1000.f);
    const float wuh = w_uh[layer * HH + h];
    const float buh = b_uh[layer];

    float hx  = h0[layer * HH + h];
    float up  = 1.f;
    float cum = 0.f;

    const int SB = 16;
    const int NB = TT / SB;              // 32 blocks, stepped 4 at a time

    PreT b0[SB], b1[SB], b2[SB], b3[SB];

#define LOADB(buf, blk)                                                   \
    {   const int _b = (blk);                                             \
        _Pragma("unroll")                                                 \
        for (int j = 0; j < SB; ++j)                                      \
            buf[j] = pre[(size_t)(_b * SB + j) * BH + idx];               \
    }

#define COMPUTEB(buf, blk)                                                \
    {   const int _t0 = (blk) * SB;                                       \
        _Pragma("unroll")                                                 \
        for (int j = 0; j < SB; ++j) {                                    \
            const int t = _t0 + j;                                        \
            const float pv    = (float)buf[j];                            \
            const float nhx   = fmaxf(fmaf(whh, hx, pv), 0.f);            \
            const float z     = fmaf(nhx, wuh, buh);                      \
            const float tilde = 1.f / (1.f + __expf(-z));                 \
            const float c     = cum + fminf(up, 1.f - cum);               \
            const float g     = rintf(c);                                 \
            const float nh    = (g > 0.5f) ? nhx   : hx;                  \
            const float nup   = (g > 0.5f) ? tilde : up;                  \
            const float ncum  = (g > 0.5f) ? 0.f   : c;                   \
            if (NTX) __builtin_nontemporal_store(nh, &xo[(size_t)t * BH + idx]); \
            else     xo[(size_t)t * BH + idx] = nh;                       \
            if (NTG) __builtin_nontemporal_store(g, &go[(size_t)t * BH + idx]);  \
            else     go[(size_t)t * BH + idx] = g;                        \
            hx = nh; up = nup; cum = ncum;                                \
        }                                                                 \
    }

    LOADB(b0, 0);
    LOADB(b1, 1);
    LOADB(b2, 2);

    for (int tb = 0; tb < NB; tb += 4) {
        if (tb + 3 < NB) LOADB(b3, tb + 3);
        COMPUTEB(b0, tb);
        if (tb + 4 < NB) LOADB(b0, tb + 4);
        COMPUTEB(b1, tb + 1);
        if (tb + 5 < NB) LOADB(b1, tb + 5);
        COMPUTEB(b2, tb + 2);
        if (tb + 6 < NB) LOADB(b2, tb + 6);
        COMPUTEB(b3, tb + 3);
    }
#undef LOADB
#undef COMPUTEB
}

// ---------------------------------------------------------------------------
// d_ws plan (ws = 1 GiB per observed fills; need ~65 MiB):
//   P0 @0, P1 @256 KB, pre0 f16 @1 MiB, pre1 f16 @33 MiB.
// d_out = pure outputs (GEMM1 reads X0 f32 directly — round-7-exact path).
// Fallback (small ws) = in-d_out plan, all f32.
// ---------------------------------------------------------------------------
extern "C" void kernel_launch(void* const* d_in, const int* in_sizes, int n_in,
                              void* d_out, int out_size, void* d_ws, size_t ws_size,
                              hipStream_t stream) {
    const float* x    = (const float*)d_in[0];
    const float* h0   = (const float*)d_in[1];
    const float* W0   = (const float*)d_in[2];
    const float* W1   = (const float*)d_in[3];
    const float* b_ih = (const float*)d_in[4];
    const float* w_hh = (const float*)d_in[5];
    const float* w_uh = (const float*)d_in[6];
    const float* b_uh = (const float*)d_in[7];

    float* out = (float*)d_out;
    float* X0 = out;
    float* X1 = out + TBH;
    float* G0 = out + 2 * TBH;
    float* G1 = out + 3 * TBH;

    const int nf0 = HH * II / 8;          // 16384
    const int nf1 = HH * HH / 8;          // 32768

    if (ws_size >= (size_t)70 * 1024 * 1024) {
        char* ws = (char*)d_ws;
        _Float16* P0   = (_Float16*)ws;
        _Float16* P1   = (_Float16*)(ws + (size_t)256 * 1024);
        _Float16* pre0 = (_Float16*)(ws + (size_t)1  * 1024 * 1024);
        _Float16* pre1 = (_Float16*)(ws + (size_t)33 * 1024 * 1024);

        pack_w2<<<(nf0 + nf1 + 255) / 256, 256, 0, stream>>>(W0, W1, P0, P1, nf0, nf1);

        gemm_f32a<_Float16><<<1024, 256, 0, stream>>>(x, P0, b_ih, pre0, MM, HH, II);
        skip_indrnn_rec<_Float16, true, true><<<BH / 64, 64, 0, stream>>>(
            pre0, h0, w_hh, w_uh, b_uh, 0, X0, G0);
        gemm_f32a<_Float16><<<1024, 256, 0, stream>>>(X0, P1, b_ih + HH, pre1, MM, HH, HH);
        skip_indrnn_rec<_Float16, true, true><<<BH / 64, 64, 0, stream>>>(
            pre1, h0, w_hh, w_uh, b_uh, 1, X1, G1);
    } else {
        _Float16* P0 = (_Float16*)X1;
        _Float16* P1 = P0 + (size_t)nf0 * 8;
        float* pre = G1;

        pack_w2<<<(nf0 + nf1 + 255) / 256, 256, 0, stream>>>(W0, W1, P0, P1, nf0, nf1);

        gemm_f32a<float><<<1024, 256, 0, stream>>>(x, P0, b_ih, pre, MM, HH, II);
        skip_indrnn_rec<float, false, true><<<BH / 64, 64, 0, stream>>>(
            pre, h0, w_hh, w_uh, b_uh, 0, X0, G0);
        gemm_f32a<float><<<1024, 256, 0, stream>>>(X0, P1, b_ih + HH, pre, MM, HH, HH);
        skip_indrnn_rec<float, true, true><<<BH / 64, 64, 0, stream>>>(
            pre, h0, w_hh, w_uh, b_uh, 1, X1, G1);
    }
}

// Round 13
// 184.431 us; speedup vs baseline: 1.2131x; 1.1249x over previous
//
#include <hip/hip_runtime.h>
#include <math.h>

#define TT 512
#define BB 64
#define II 256
#define HH 512
#define BH (BB*HH)           // 32768
#define TBH ((size_t)TT*BH)  // 16777216
#define MM (TT*BB)           // 32768

typedef float f32x4 __attribute__((ext_vector_type(4)));
typedef _Float16 f16x8 __attribute__((ext_vector_type(8)));
typedef unsigned short u16;

// ---------------------------------------------------------------------------
// Pack W0,W1 [N][K] f32 -> fragment-major f16 (8 f16 = 16 B per fragment)
// ---------------------------------------------------------------------------
__global__ __launch_bounds__(256)
void pack_w2(const float* __restrict__ W0, const float* __restrict__ W1,
             _Float16* __restrict__ P0, _Float16* __restrict__ P1,
             int nf0, int nf1)
{
    const int i = blockIdx.x * 256 + threadIdx.x;
    const float* src; _Float16* dst;
    if (i < nf0) { src = W0 + (size_t)i * 8;  dst = P0 + (size_t)i * 8; }
    else         { const int j = i - nf0; if (j >= nf1) return;
                   src = W1 + (size_t)j * 8;  dst = P1 + (size_t)j * 8; }
    f16x8 h8;
#pragma unroll
    for (int j = 0; j < 8; ++j) h8[j] = (_Float16)src[j];
    *(f16x8*)dst = h8;
}

// ---------------------------------------------------------------------------
// GEMM, A = f32 (reg-staged, cvt f16 during LDS stage; round-7 proven).
//   C[M][N] = A[M][K] * W_f16[N][K]^T + bias   (f32 out)
// 128x128 tile, BK=32, 4 waves (2x2), 4x4 16x16x32 f16 frags.
// A-prefetch for kt+1 issued before the MFMA block (latency overlapped).
// Tile order: bn-major + XCD-clustered.
// ---------------------------------------------------------------------------
__global__ __launch_bounds__(256, 4)
void gemm_f32a(const float* __restrict__ A, const _Float16* __restrict__ Bp,
               const float* __restrict__ bias, float* __restrict__ C,
               int M, int N, int K)
{
    const int K8 = K >> 3;
    __shared__ _Float16 As[128][40];   // padded: row stride 80 B

    const int tid  = threadIdx.x;
    const int lane = tid & 63;
    const int wid  = tid >> 6;
    const int wr   = wid >> 1, wc = wid & 1;

    const int nbn = N >> 7;
    const int nt  = (M >> 7) * nbn;
    const int per = nt >> 3;
    const int logical = (blockIdx.x & 7) * per + (blockIdx.x >> 3);
    const int bm = logical / nbn;
    const int bn = logical % nbn;
    const int row0 = bm * 128;
    const int col0 = bn * 128;

    const int s_row = tid >> 1;
    const int s_kh  = (tid & 1) * 16;
    const float* Ap = A + (size_t)(row0 + s_row) * K + s_kh;

    const int fr  = lane & 15;
    const int q   = lane >> 4;
    const int ko8 = q * 8;

    f32x4 acc[4][4];
#pragma unroll
    for (int m = 0; m < 4; ++m)
#pragma unroll
        for (int n = 0; n < 4; ++n)
#pragma unroll
            for (int r = 0; r < 4; ++r) acc[m][n][r] = 0.f;

    const _Float16* bbase[4];
#pragma unroll
    for (int n = 0; n < 4; ++n) {
        const int col = col0 + wc * 64 + n * 16 + fr;
        bbase[n] = Bp + ((size_t)col * K8 + q) * 8;
    }

    f32x4 a_ld[4];
#pragma unroll
    for (int qq = 0; qq < 4; ++qq) a_ld[qq] = *(const f32x4*)(Ap + qq * 4);

    const int nkt = K >> 5;
    for (int kt = 0; kt < nkt; ++kt) {
        __syncthreads();
#pragma unroll
        for (int half = 0; half < 2; ++half) {
            f16x8 h8;
#pragma unroll
            for (int j = 0; j < 8; ++j)
                h8[j] = (_Float16)a_ld[half * 2 + (j >> 2)][j & 3];
            *(f16x8*)&As[s_row][s_kh + half * 8] = h8;
        }
        __syncthreads();

        f16x8 bfr[4];
#pragma unroll
        for (int n = 0; n < 4; ++n)
            bfr[n] = *(const f16x8*)(bbase[n] + (size_t)kt * 32);

        if (kt + 1 < nkt) {
            const float* apn = Ap + (size_t)(kt + 1) * 32;
#pragma unroll
            for (int qq = 0; qq < 4; ++qq) a_ld[qq] = *(const f32x4*)(apn + qq * 4);
        }

#pragma unroll
        for (int m = 0; m < 4; ++m) {
            const int row = wr * 64 + m * 16 + fr;
            f16x8 af = *(const f16x8*)&As[row][ko8];
#pragma unroll
            for (int n = 0; n < 4; ++n)
                acc[m][n] = __builtin_amdgcn_mfma_f32_16x16x32_f16(af, bfr[n], acc[m][n], 0, 0, 0);
        }
    }

#pragma unroll
    for (int n = 0; n < 4; ++n) {
        const int gc = col0 + wc * 64 + n * 16 + fr;
        const float bj = bias[gc];
#pragma unroll
        for (int m = 0; m < 4; ++m) {
            const int gr0 = row0 + wr * 64 + m * 16 + q * 4;
#pragma unroll
            for (int r = 0; r < 4; ++r)
                C[(size_t)(gr0 + r) * N + gc] = acc[m][n][r] + bj;
        }
    }
}

// ---------------------------------------------------------------------------
// Recurrence: one thread per (b,h) — 512 waves = max TLP (round-11 lesson:
// never trade wave count for per-thread width here). 16-step blocks,
// 4-deep MANUAL pipeline with named buffers b0..b3 (no rotation moves;
// loads issue >=3 blocks (~1500 cy) before first use — round-10 proven).
// pre (f32) aliases go: reads of block tb happen >=3 blocks before writes
// to tb (same thread, program order).
// NTX only when xo is NOT re-read downstream (round-12 lesson: NT-storing
// GEMM1's input forces a full-HBM refetch).
// ---------------------------------------------------------------------------
template<bool NTX, bool NTG>
__global__ __launch_bounds__(64)
void skip_indrnn_rec(const float* __restrict__ pre, const float* __restrict__ h0,
                     const float* __restrict__ w_hh, const float* __restrict__ w_uh,
                     const float* __restrict__ b_uh, int layer,
                     float* __restrict__ xo, float* __restrict__ go)
{
    const int idx = blockIdx.x * 64 + threadIdx.x;
    const int h = idx & (HH - 1);

    float whh = w_hh[layer * HH + h];
    whh = fminf(fmaxf(whh, -1000.f), 1000.f);
    const float wuh = w_uh[layer * HH + h];
    const float buh = b_uh[layer];

    float hx  = h0[layer * HH + h];
    float up  = 1.f;
    float cum = 0.f;

    const int SB = 16;
    const int NB = TT / SB;              // 32 blocks, stepped 4 at a time

    float b0[SB], b1[SB], b2[SB], b3[SB];

#define LOADB(buf, blk)                                                   \
    {   const int _b = (blk);                                             \
        _Pragma("unroll")                                                 \
        for (int j = 0; j < SB; ++j)                                      \
            buf[j] = pre[(size_t)(_b * SB + j) * BH + idx];               \
    }

#define COMPUTEB(buf, blk)                                                \
    {   const int _t0 = (blk) * SB;                                       \
        _Pragma("unroll")                                                 \
        for (int j = 0; j < SB; ++j) {                                    \
            const int t = _t0 + j;                                        \
            const float nhx   = fmaxf(fmaf(whh, hx, buf[j]), 0.f);        \
            const float z     = fmaf(nhx, wuh, buh);                      \
            const float tilde = 1.f / (1.f + __expf(-z));                 \
            const float c     = cum + fminf(up, 1.f - cum);               \
            const float g     = rintf(c);                                 \
            const float nh    = (g > 0.5f) ? nhx   : hx;                  \
            const float nup   = (g > 0.5f) ? tilde : up;                  \
            const float ncum  = (g > 0.5f) ? 0.f   : c;                   \
            if (NTX) __builtin_nontemporal_store(nh, &xo[(size_t)t * BH + idx]); \
            else     xo[(size_t)t * BH + idx] = nh;                       \
            if (NTG) __builtin_nontemporal_store(g, &go[(size_t)t * BH + idx]);  \
            else     go[(size_t)t * BH + idx] = g;                        \
            hx = nh; up = nup; cum = ncum;                                \
        }                                                                 \
    }

    LOADB(b0, 0);
    LOADB(b1, 1);
    LOADB(b2, 2);

    for (int tb = 0; tb < NB; tb += 4) {
        if (tb + 3 < NB) LOADB(b3, tb + 3);
        COMPUTEB(b0, tb);
        if (tb + 4 < NB) LOADB(b0, tb + 4);
        COMPUTEB(b1, tb + 1);
        if (tb + 5 < NB) LOADB(b1, tb + 5);
        COMPUTEB(b2, tb + 2);
        if (tb + 6 < NB) LOADB(b2, tb + 6);
        COMPUTEB(b3, tb + 3);
    }
#undef LOADB
#undef COMPUTEB
}

// ---------------------------------------------------------------------------
// Plan (round-7 dataflow + round-10 rec pipeline):
//  X0 = xo0 (regular stores — GEMM1 re-reads it)    G0 = g0 (NT)
//  X1 = xo1 (NT)                                    G1 = g1 (NT; holds f32
//       pre0 then pre1 scratch, per-thread alias with >=3-block separation)
//  Packed W -> d_ws if present, else head of X1 (dead until rec1).
// ---------------------------------------------------------------------------
extern "C" void kernel_launch(void* const* d_in, const int* in_sizes, int n_in,
                              void* d_out, int out_size, void* d_ws, size_t ws_size,
                              hipStream_t stream) {
    const float* x    = (const float*)d_in[0];
    const float* h0   = (const float*)d_in[1];
    const float* W0   = (const float*)d_in[2];
    const float* W1   = (const float*)d_in[3];
    const float* b_ih = (const float*)d_in[4];
    const float* w_hh = (const float*)d_in[5];
    const float* w_uh = (const float*)d_in[6];
    const float* b_uh = (const float*)d_in[7];

    float* out = (float*)d_out;
    float* X0 = out;
    float* X1 = out + TBH;
    float* G0 = out + 2 * TBH;
    float* G1 = out + 3 * TBH;

    const int nf0 = HH * II / 8;          // 16384
    const int nf1 = HH * HH / 8;          // 32768

    _Float16* P0;
    if (ws_size >= (size_t)(nf0 + nf1) * 16) P0 = (_Float16*)d_ws;
    else                                     P0 = (_Float16*)X1;   // dead until rec1
    _Float16* P1 = P0 + (size_t)nf0 * 8;
    float* pre = G1;

    pack_w2<<<(nf0 + nf1 + 255) / 256, 256, 0, stream>>>(W0, W1, P0, P1, nf0, nf1);

    gemm_f32a<<<1024, 256, 0, stream>>>(x, P0, b_ih, pre, MM, HH, II);
    skip_indrnn_rec<false, true><<<BH / 64, 64, 0, stream>>>(
        pre, h0, w_hh, w_uh, b_uh, 0, X0, G0);
    gemm_f32a<<<1024, 256, 0, stream>>>(X0, P1, b_ih + HH, pre, MM, HH, HH);
    skip_indrnn_rec<true, true><<<BH / 64, 64, 0, stream>>>(
        pre, h0, w_hh, w_uh, b_uh, 1, X1, G1);
}